// Round 19
// baseline (998.176 us; speedup 1.0000x reference)
//
#include <hip/hip_runtime.h>
#include <hip/hip_bf16.h>
#include <math.h>

typedef __hip_bfloat16 bf16;
typedef __bf16 bf16x8 __attribute__((ext_vector_type(8)));
typedef float f32x4 __attribute__((ext_vector_type(4)));

#define HH 56
#define WW 56
#define WSZ 7
#define SSH 3
#define NHEAD 12
#define CDIM 384
#define BBATCH 32
#define NTOK 49
#define NWIN 64
#define HIDD 1536
#define HD 32
#define NWTOT (BBATCH*NWIN)
#define MROWS (NWTOT*NTOK)        /* 100352 */
#define MHALF (MROWS/2)           /* 50176 */
#define LTOT (HH*WW)
#define EPSLN 1e-5f
#define QSCALE 0.17677669529663687f
#define NEGBIG -1e30f

enum { M_QK = 0, M_V = 1, M_FC1 = 2 };

__device__ __forceinline__ void gload16(const void* g, void* l) {
    __builtin_amdgcn_global_load_lds(
        (const __attribute__((address_space(1))) void*)g,
        (__attribute__((address_space(3))) void*)l, 16, 0, 0);
}

__device__ __forceinline__ unsigned short bfbits(float v) {
    bf16 b = __float2bfloat16(v);
    return *reinterpret_cast<unsigned short*>(&b);
}

__device__ __forceinline__ float fast_gelu(float v) {
    return v / (1.0f + __expf(-1.59576912f * v * fmaf(0.044715f, v * v, 1.0f)));
}

__device__ __forceinline__ int xcd_swz(int orig, int nwg) {
    const int q = nwg >> 3, r = nwg & 7;
    const int xcd = orig & 7, loc = orig >> 3;
    return (xcd < r ? xcd * (q + 1) : r * (q + 1) + (xcd - r) * q) + loc;
}

// ---------------------------------------------------------------------------
__global__ __launch_bounds__(256)
void cvt4_k(const float* __restrict__ s0, const float* __restrict__ s1,
            const float* __restrict__ s2, const float* __restrict__ s3,
            bf16* __restrict__ d0, bf16* __restrict__ d1,
            bf16* __restrict__ d2, bf16* __restrict__ d3) {
    int i = blockIdx.x * 256 + threadIdx.x;          // 1,769,472 total
    if (i < 442368)        d0[i] = __float2bfloat16(s0[i]);
    else if (i < 589824)  { int j = i - 442368;  d1[j] = __float2bfloat16(s1[j]); }
    else if (i < 1179648) { int j = i - 589824;  d2[j] = __float2bfloat16(s2[j]); }
    else                  { int j = i - 1179648; d3[j] = __float2bfloat16(s3[j]); }
}

__global__ __launch_bounds__(256)
void tbl_k(const float* __restrict__ rpb, const int* __restrict__ relidx,
           const float* __restrict__ amask, float* __restrict__ tbl) {
    int idx = blockIdx.x * 256 + threadIdx.x;
    int m = idx & 63, n = (idx >> 6) & 63;
    int h = (idx >> 12) % NHEAD, wi = idx / (64 * 64 * NHEAD);
    float v;
    if (m >= NTOK) v = NEGBIG;
    else if (n >= NTOK) v = 0.f;
    else v = rpb[relidx[n * NTOK + m] * NHEAD + h] + amask[((long)wi * NTOK + n) * NTOK + m];
    tbl[idx] = v;
}

__global__ __launch_bounds__(256) void gather_k(const float* __restrict__ x,
                                                bf16* __restrict__ xw, int rbase) {
    int idx = blockIdx.x * 256 + threadIdx.x;
    int rr_l = idx / 96, c4 = (idx % 96) * 4;
    int rr = rbase + rr_l;
    int w = rr / 49, ti = rr % 49;
    int b = w >> 6, wi = w & 63;
    int hy = (wi >> 3) * 7 + ti / 7;
    int hx = (wi & 7) * 7 + ti % 7;
    int sh = hy + SSH; if (sh >= HH) sh -= HH;
    int sw = hx + SSH; if (sw >= WW) sw -= WW;
    float4 v = *(const float4*)&x[((long)b * LTOT + sh * WW + sw) * CDIM + c4];
    ushort4 u = { bfbits(v.x), bfbits(v.y), bfbits(v.z), bfbits(v.w) };
    *(ushort4*)&xw[(long)rr_l * CDIM + c4] = u;
}

// ---------------------------------------------------------------------------
// BARRIER-FREE wave-autonomous MFMA GEMM. Block 128x128 (4 waves, 2x2); each
// wave owns its 64x64 tile AND private LDS staging (A 64x32 + B 64x32, single
// buffer, 8 KB/wave -> 32 KB/block). Staging global->reg->LDS; correctness by
// program order + in-order per-wave DS completion (reads of tile t precede
// writes of t+1; LDS aliasing forbids reorder). ZERO s_barrier in kernel.
// (256,3): VGPR cap ~168 covers acc64+frags32+stage32. Same XOR swizzle both
// sides; each wave b128 LDS op covers a contiguous 1KB tile (conflict-free).
// ---------------------------------------------------------------------------
template<int MODE, int KDIM, int NTN>
__global__ __launch_bounds__(256, 3)
void wgemm_k(const bf16* __restrict__ A, const bf16* __restrict__ Wt,
             const float* __restrict__ bias, void* __restrict__ Outp)
{
    constexpr bool SWAP = (MODE != M_V);
    __shared__ bf16 lds[4][2][64 * 32];   // [wave][A|B][row*32+elem] = 32 KB
    const int tid = threadIdx.x;
    const int wid = tid >> 6, lane = tid & 63;

    const int gid = xcd_swz(blockIdx.x, gridDim.x);
    const int m0 = (gid / NTN) * 128;
    const int n0 = (gid % NTN) * 128;

    const int wr = (wid >> 1) * 64, wc = (wid & 1) * 64;
    const int srow = lane >> 2, sseg = lane & 3;     // staging: 16 rows/issue
    const bf16* Ag = A + (long)(m0 + wr + srow) * KDIM + sseg * 8;
    const bf16* Wg = Wt + (long)(n0 + wc + srow) * KDIM + sseg * 8;
    bf16* Al = &lds[wid][0][0];
    bf16* Bl = &lds[wid][1][0];

    const int l15 = lane & 15, g4 = lane >> 4;

    f32x4 acc[4][4] = {};
    bf16x8 ar[4], br[4];

    auto LOADA = [&](int t) {
#pragma unroll
        for (int i = 0; i < 4; ++i)
            ar[i] = *(const bf16x8*)(Ag + (long)(i * 16) * KDIM + t * 32);
    };
    auto LOADB = [&](int t) {
#pragma unroll
        for (int i = 0; i < 4; ++i)
            br[i] = *(const bf16x8*)(Wg + (long)(i * 16) * KDIM + t * 32);
    };
    auto WRA = [&]() {
#pragma unroll
        for (int i = 0; i < 4; ++i) {
            const int r = srow + 16 * i;
            *(bf16x8*)&Al[r * 32 + (sseg ^ ((r >> 1) & 3)) * 8] = ar[i];
        }
    };
    auto WRB = [&]() {
#pragma unroll
        for (int i = 0; i < 4; ++i) {
            const int r = srow + 16 * i;
            *(bf16x8*)&Bl[r * 32 + (sseg ^ ((r >> 1) & 3)) * 8] = br[i];
        }
    };

    const int nt = KDIM / 32;
    LOADA(0); LOADB(0);
    WRA(); WRB();                          // compiler inserts vmcnt before use
    for (int t = 0; t < nt; ++t) {
        if (t + 1 < nt) { LOADA(t + 1); LOADB(t + 1); }   // hide latency under frags+MFMA
        bf16x8 af[4], bfr[4];
#pragma unroll
        for (int i = 0; i < 4; ++i) {
            const int ra = i * 16 + l15;
            const int sa = g4 ^ ((ra >> 1) & 3);
            af[i]  = *(const bf16x8*)&Al[ra * 32 + sa * 8];
            bfr[i] = *(const bf16x8*)&Bl[ra * 32 + sa * 8];
        }
        if (t + 1 < nt) { WRA(); WRB(); }  // DS in-order: executes after reads
#pragma unroll
        for (int mi = 0; mi < 4; ++mi)
#pragma unroll
            for (int ni = 0; ni < 4; ++ni) {
                if (SWAP)
                    acc[ni][mi] = __builtin_amdgcn_mfma_f32_16x16x32_bf16(
                        bfr[ni], af[mi], acc[ni][mi], 0, 0, 0);
                else
                    acc[mi][ni] = __builtin_amdgcn_mfma_f32_16x16x32_bf16(
                        af[mi], bfr[ni], acc[mi][ni], 0, 0, 0);
            }
    }

    if (MODE == M_V) {
#pragma unroll
        for (int mi = 0; mi < 4; ++mi) {
            const int mb = m0 + wr + mi * 16 + g4 * 4;
            const int wv_ = mb / 49, ti0 = mb - wv_ * 49;
#pragma unroll
            for (int ni = 0; ni < 4; ++ni) {
                const int n = n0 + wc + ni * 16 + l15;
                const int h = n >> 5, d = n & 31;
                const float bn = bias[n];
                float v4[4];
#pragma unroll
                for (int j = 0; j < 4; ++j) v4[j] = acc[mi][ni][j] + bn;
                if (ti0 <= 45) {
                    ushort4 u = { bfbits(v4[0]), bfbits(v4[1]), bfbits(v4[2]), bfbits(v4[3]) };
                    *(ushort4*)&((bf16*)Outp)[(((long)wv_ * NHEAD + h) * HD + d) * 64 + ti0] = u;
                } else {
#pragma unroll
                    for (int j = 0; j < 4; ++j) {
                        const int m = mb + j;
                        const int w2 = m / 49, ti = m - w2 * 49;
                        ((bf16*)Outp)[(((long)w2 * NHEAD + h) * HD + d) * 64 + ti]
                            = __float2bfloat16(v4[j]);
                    }
                }
            }
        }
    } else {
        long rowbase[4];
        int wq_[4], ti_[4];
#pragma unroll
        for (int mi = 0; mi < 4; ++mi) {
            const int m = m0 + wr + mi * 16 + l15;
            if (MODE == M_QK) { wq_[mi] = m / 49; ti_[mi] = m - wq_[mi] * 49; }
            else              { rowbase[mi] = (long)m * HIDD; }
        }
#pragma unroll
        for (int ni = 0; ni < 4; ++ni) {
            const int nb = n0 + wc + ni * 16 + g4 * 4;
            const float4 bn = *(const float4*)&bias[nb];
            const float bb[4] = { bn.x, bn.y, bn.z, bn.w };
#pragma unroll
            for (int mi = 0; mi < 4; ++mi) {
                float v4[4];
#pragma unroll
                for (int j = 0; j < 4; ++j) v4[j] = acc[ni][mi][j] + bb[j];
                if (MODE == M_FC1) {
#pragma unroll
                    for (int j = 0; j < 4; ++j) v4[j] = fast_gelu(v4[j]);
                } else if (MODE == M_QK) {
                    if (nb < CDIM) {
#pragma unroll
                        for (int j = 0; j < 4; ++j) v4[j] *= QSCALE;
                    }
                }
                ushort4 u = { bfbits(v4[0]), bfbits(v4[1]), bfbits(v4[2]), bfbits(v4[3]) };
                if (MODE == M_QK) {
                    const int which = nb >= CDIM;
                    const int hb = (nb - which * CDIM) >> 5, d0 = nb & 31;
                    *(ushort4*)&((bf16*)Outp)[
                        ((((long)wq_[mi] * 2 + which) * NHEAD + hb) * NTOK + ti_[mi]) * HD + d0] = u;
                } else {
                    *(ushort4*)&((bf16*)Outp)[rowbase[mi] + nb] = u;
                }
            }
        }
    }
}

// ---------------------------------------------------------------------------
// Fused GEMM(128 x 384 x K) + row-LayerNorm + residual (R12/R16 best shape,
// 886 us reproduced 3x — left untouched).
// ---------------------------------------------------------------------------
template<int KDIM, bool SCATTER>
__global__ __launch_bounds__(512, 2)
void gemm_ln_k(const bf16* __restrict__ A, const bf16* __restrict__ Wt,
               const float* __restrict__ bias, const bf16* __restrict__ resid,
               const float* __restrict__ lng, const float* __restrict__ lnb,
               float* __restrict__ outf, bf16* __restrict__ outb, int mbase)
{
    __shared__ bf16 As[2][128 * 32];     // 16 KB
    __shared__ bf16 Bs[2][384 * 32];     // 48 KB
    __shared__ float lnp[1024];          // 4 KB
    const int tid = threadIdx.x;
    const int wid = tid >> 6, lane = tid & 63;

    const int m0 = xcd_swz(blockIdx.x, gridDim.x) * 128;

    const int strow = tid >> 2, stseg = tid & 3;
    const int sws = stseg ^ ((strow >> 1) & 3);
    const bf16* Ag = A + (long)(m0 + strow) * KDIM + sws * 8;
    const bf16* Wg = Wt + (long)strow * KDIM + sws * 8;

    const int wm = wid >> 2, wn = wid & 3;
    const int wr = wm * 64, wc = wn * 96;
    const int l15 = lane & 15, g4 = lane >> 4;
    const int sa = g4 ^ ((l15 >> 1) & 3);

    f32x4 acc[6][4] = {};

    auto STAGE = [&](int b, int t) {
        gload16(Ag + t * 32, &As[b][strow * 32 + stseg * 8]);
#pragma unroll
        for (int p = 0; p < 3; ++p)
            gload16(Wg + (long)(p * 128) * KDIM + t * 32,
                    &Bs[b][(p * 128 + strow) * 32 + stseg * 8]);
    };

    const int nt = KDIM / 32;
    STAGE(0, 0);
    STAGE(1, 1);
    asm volatile("s_waitcnt vmcnt(4)" ::: "memory");
    __builtin_amdgcn_s_barrier();

    int buf = 0;
    for (int t = 0; t < nt; ++t) {
        bf16x8 af[4], bfr[6];
#pragma unroll
        for (int i = 0; i < 4; ++i)
            af[i] = *(const bf16x8*)&As[buf][(wr + i * 16 + l15) * 32 + sa * 8];
#pragma unroll
        for (int i = 0; i < 6; ++i)
            bfr[i] = *(const bf16x8*)&Bs[buf][(wc + i * 16 + l15) * 32 + sa * 8];
        __builtin_amdgcn_sched_barrier(0);
        asm volatile("s_waitcnt lgkmcnt(0)" ::: "memory");
        __builtin_amdgcn_sched_barrier(0);
        __builtin_amdgcn_s_barrier();
        if (t + 2 < nt) STAGE(buf, t + 2);
#pragma unroll
        for (int ni = 0; ni < 6; ++ni)
#pragma unroll
            for (int mi = 0; mi < 4; ++mi)
                acc[ni][mi] = __builtin_amdgcn_mfma_f32_16x16x32_bf16(
                    bfr[ni], af[mi], acc[ni][mi], 0, 0, 0);
        if (t + 2 < nt) { asm volatile("s_waitcnt vmcnt(4)" ::: "memory"); }
        else            { asm volatile("s_waitcnt vmcnt(0)" ::: "memory"); }
        __builtin_amdgcn_s_barrier();
        buf ^= 1;
    }

    float psum[4] = {}, psq[4] = {};
#pragma unroll
    for (int ni = 0; ni < 6; ++ni) {
        const int nb = wc + ni * 16 + g4 * 4;
        const float4 bn = *(const float4*)&bias[nb];
        const float bb[4] = { bn.x, bn.y, bn.z, bn.w };
#pragma unroll
        for (int mi = 0; mi < 4; ++mi)
#pragma unroll
            for (int j = 0; j < 4; ++j) {
                float v = acc[ni][mi][j] + bb[j];
                acc[ni][mi][j] = v;
                psum[mi] += v; psq[mi] += v * v;
            }
    }
#pragma unroll
    for (int mi = 0; mi < 4; ++mi) {
        psum[mi] += __shfl_xor(psum[mi], 16); psum[mi] += __shfl_xor(psum[mi], 32);
        psq[mi]  += __shfl_xor(psq[mi], 16);  psq[mi]  += __shfl_xor(psq[mi], 32);
    }
    if (g4 == 0) {
#pragma unroll
        for (int mi = 0; mi < 4; ++mi) {
            const int r = wr + mi * 16 + l15;
            lnp[wn * 128 + r] = psum[mi];
            lnp[512 + wn * 128 + r] = psq[mi];
        }
    }
    __syncthreads();

#pragma unroll
    for (int mi = 0; mi < 4; ++mi) {
        const int r = wr + mi * 16 + l15;
        const float s  = lnp[r] + lnp[128 + r] + lnp[256 + r] + lnp[384 + r];
        const float sq = lnp[512 + r] + lnp[640 + r] + lnp[768 + r] + lnp[896 + r];
        const float mean = s * (1.f / 384.f);
        const float rstd = rsqrtf(sq * (1.f / 384.f) - mean * mean + EPSLN);

        const long rl = m0 + r;
        long dst;
        if (SCATTER) {
            const int m = mbase + (int)rl;
            int w = m / 49, ti = m - w * 49;
            int b = w >> 6, wi = w & 63;
            int hy = (wi >> 3) * 7 + ti / 7;
            int hx = (wi & 7) * 7 + ti % 7;
            int dh = hy + SSH; if (dh >= HH) dh -= HH;
            int dw = hx + SSH; if (dw >= WW) dw -= WW;
            dst = (long)b * LTOT + dh * WW + dw - mbase;
        } else {
            dst = mbase + rl;
        }
#pragma unroll
        for (int ni = 0; ni < 6; ++ni) {
            const int c = wc + ni * 16 + g4 * 4;
            const float4 gv = *(const float4*)&lng[c];
            const float4 bv = *(const float4*)&lnb[c];
            ushort4 xv = *(const ushort4*)&resid[rl * CDIM + c];
            float x0 = __bfloat162float(*(bf16*)&xv.x);
            float x1 = __bfloat162float(*(bf16*)&xv.y);
            float x2 = __bfloat162float(*(bf16*)&xv.z);
            float x3 = __bfloat162float(*(bf16*)&xv.w);
            float r0 = x0 + (acc[ni][mi][0] - mean) * rstd * gv.x + bv.x;
            float r1 = x1 + (acc[ni][mi][1] - mean) * rstd * gv.y + bv.y;
            float r2 = x2 + (acc[ni][mi][2] - mean) * rstd * gv.z + bv.z;
            float r3 = x3 + (acc[ni][mi][3] - mean) * rstd * gv.w + bv.w;
            if (SCATTER) {
                ushort4 u = { bfbits(r0), bfbits(r1), bfbits(r2), bfbits(r3) };
                *(ushort4*)&outb[dst * CDIM + c] = u;
            } else {
                float4 o = { r0, r1, r2, r3 };
                *(float4*)&outf[dst * CDIM + c] = o;
            }
        }
    }
}

// ---------------------------------------------------------------------------
// MFMA attention: 4 waves/block, each wave = one (window, head). Unchanged.
// ---------------------------------------------------------------------------
__global__ __launch_bounds__(256)
void mattn_k(const bf16* __restrict__ qk, const bf16* __restrict__ vT,
             const float* __restrict__ tbl, bf16* __restrict__ attn_out)
{
    __shared__ bf16 Plds[4][64 * 72];
    const int tid = threadIdx.x, wid = tid >> 6, lane = tid & 63;
    const int t = blockIdx.x * 4 + wid;
    const int w = t / NHEAD, h = t % NHEAD, wi = w & 63;
    const int l15 = lane & 15, g = lane >> 4;
    const bf16* qb = qk + ((long)(w * 2 + 0) * NHEAD + h) * (NTOK * HD);
    const bf16* kb = qk + ((long)(w * 2 + 1) * NHEAD + h) * (NTOK * HD);
    const bf16* vt = vT + ((long)w * NHEAD + h) * (HD * 64);
    const float* Tb = tbl + (long)(wi * NHEAD + h) * 64 * 64;
    char* Pw = (char*)&Plds[wid][0];

    bf16x8 kf[4], qf[4];
#pragma unroll
    for (int i = 0; i < 4; ++i) {
        kf[i] = *(const bf16x8*)&kb[(16 * i + l15) * HD + 8 * g];
        qf[i] = *(const bf16x8*)&qb[(16 * i + l15) * HD + 8 * g];
    }
    f32x4 s[4][4] = {};
#pragma unroll
    for (int mi = 0; mi < 4; ++mi)
#pragma unroll
        for (int ni = 0; ni < 4; ++ni)
            s[mi][ni] = __builtin_amdgcn_mfma_f32_16x16x32_bf16(
                kf[mi], qf[ni], s[mi][ni], 0, 0, 0);

#pragma unroll
    for (int ni = 0; ni < 4; ++ni) {
        const int n = 16 * ni + l15;
#pragma unroll
        for (int mi = 0; mi < 4; ++mi) {
            float4 tv = *(const float4*)&Tb[(long)n * 64 + 16 * mi + 4 * g];
            s[mi][ni][0] += tv.x; s[mi][ni][1] += tv.y;
            s[mi][ni][2] += tv.z; s[mi][ni][3] += tv.w;
        }
        float mx = NEGBIG;
#pragma unroll
        for (int mi = 0; mi < 4; ++mi)
#pragma unroll
            for (int j = 0; j < 4; ++j) mx = fmaxf(mx, s[mi][ni][j]);
        mx = fmaxf(mx, __shfl_xor(mx, 16));
        mx = fmaxf(mx, __shfl_xor(mx, 32));
        float sum = 0.f;
#pragma unroll
        for (int mi = 0; mi < 4; ++mi)
#pragma unroll
            for (int j = 0; j < 4; ++j) {
                float e = expf(s[mi][ni][j] - mx);
                s[mi][ni][j] = e; sum += e;
            }
        sum += __shfl_xor(sum, 16);
        sum += __shfl_xor(sum, 32);
        const float r = 1.0f / sum;
#pragma unroll
        for (int mi = 0; mi < 4; ++mi) {
            ushort4 u;
            u.x = bfbits(s[mi][ni][0] * r);
            u.y = bfbits(s[mi][ni][1] * r);
            u.z = bfbits(s[mi][ni][2] * r);
            u.w = bfbits(s[mi][ni][3] * r);
            *(ushort4*)(Pw + (long)n * 144 + (16 * mi + 4 * g) * 2) = u;
        }
    }

    f32x4 o[4][2] = {};
#pragma unroll
    for (int kk = 0; kk < 2; ++kk) {
        bf16x8 vf[2];
        vf[0] = *(const bf16x8*)&vt[(long)(l15) * 64 + 32 * kk + 8 * g];
        vf[1] = *(const bf16x8*)&vt[(long)(16 + l15) * 64 + 32 * kk + 8 * g];
#pragma unroll
        for (int rt = 0; rt < 4; ++rt) {
            bf16x8 pf = *(const bf16x8*)(Pw + (long)(16 * rt + l15) * 144 + (32 * kk + 8 * g) * 2);
            o[rt][0] = __builtin_amdgcn_mfma_f32_16x16x32_bf16(pf, vf[0], o[rt][0], 0, 0, 0);
            o[rt][1] = __builtin_amdgcn_mfma_f32_16x16x32_bf16(pf, vf[1], o[rt][1], 0, 0, 0);
        }
    }

#pragma unroll
    for (int rt = 0; rt < 4; ++rt)
#pragma unroll
        for (int dt = 0; dt < 2; ++dt)
#pragma unroll
            for (int j = 0; j < 4; ++j) {
                int n = 16 * rt + 4 * g + j;
                if (n < NTOK)
                    attn_out[((long)w * NTOK + n) * CDIM + h * HD + 16 * dt + l15]
                        = __float2bfloat16(o[rt][dt][j]);
            }
}

extern "C" void kernel_launch(void* const* d_in, const int* in_sizes, int n_in,
                              void* d_out, int out_size, void* d_ws, size_t ws_size,
                              hipStream_t stream)
{
    const float* x      = (const float*)d_in[0];
    const float* qkv_w  = (const float*)d_in[1];
    const float* qkv_b  = (const float*)d_in[2];
    const float* proj_w = (const float*)d_in[3];
    const float* proj_b = (const float*)d_in[4];
    const float* rpb    = (const float*)d_in[5];
    const float* ln1_g  = (const float*)d_in[6];
    const float* ln1_b  = (const float*)d_in[7];
    const float* fc1_w  = (const float*)d_in[8];
    const float* fc1_b  = (const float*)d_in[9];
    const float* fc2_w  = (const float*)d_in[10];
    const float* fc2_b  = (const float*)d_in[11];
    const float* ln2_g  = (const float*)d_in[12];
    const float* ln2_b  = (const float*)d_in[13];
    const float* amask  = (const float*)d_in[14];
    const int*   relidx = (const int*)d_in[15];
    float* out = (float*)d_out;
    char*  ws  = (char*)d_ws;

    // workspace layout (half-pipelined; peak 259,129,344 B)
    bf16*  wq    = (bf16*) (ws + 0L);
    bf16*  wp    = (bf16*) (ws + 884736L);
    bf16*  w1    = (bf16*) (ws + 1179648L);
    bf16*  w2    = (bf16*) (ws + 2359296L);
    float* tbl   = (float*)(ws + 3538944L);
    bf16*  xw_h  = (bf16*) (ws + 16121856L);
    bf16*  qkb_h = (bf16*) (ws + 54657024L);
    bf16*  vT_h  = (bf16*) (ws + 131727360L);
    bf16*  att_h = (bf16*) (ws + 182059008L);
    bf16*  x1b_h = (bf16*) (ws + 220594176L);
    bf16*  H1_h  = (bf16*) (ws + 16121856L);

    dim3 b256(256), b512(512);

    cvt4_k<<<dim3(1769472 / 256), b256, 0, stream>>>(
        qkv_w, proj_w, fc1_w, fc2_w, wq, wp, w1, w2);
    tbl_k<<<dim3(64*12*64*64/256), b256, 0, stream>>>(rpb, relidx, amask, tbl);

    for (int c = 0; c < 2; ++c) {
        const int mb = c * MHALF;
        gather_k<<<dim3(MHALF * 96 / 256), b256, 0, stream>>>(x, xw_h, mb);
        wgemm_k<M_QK, CDIM, 6><<<dim3((MHALF/128)*6), b256, 0, stream>>>(
            xw_h, wq, qkv_b, (void*)qkb_h);
        wgemm_k<M_V, CDIM, 3><<<dim3((MHALF/128)*3), b256, 0, stream>>>(
            xw_h, wq + (long)2*CDIM*CDIM, qkv_b + 2*CDIM, (void*)vT_h);
        mattn_k<<<dim3(1024 * NHEAD / 4), b256, 0, stream>>>(qkb_h, vT_h, tbl, att_h);
        // PROJ + LN1 + residual(xw) + window-reverse scatter -> x1b (bf16)
        gemm_ln_k<CDIM, true><<<dim3(MHALF/128), b512, 0, stream>>>(
            att_h, wp, proj_b, xw_h, ln1_g, ln1_b, nullptr, x1b_h, mb);
        // FC1 + fast-gelu -> H1
        wgemm_k<M_FC1, CDIM, 12><<<dim3((MHALF/128)*12), b256, 0, stream>>>(
            x1b_h, w1, fc1_b, (void*)H1_h);
        // FC2 + LN2 + residual(x1b) -> out (fp32)
        gemm_ln_k<HIDD, false><<<dim3(MHALF/128), b512, 0, stream>>>(
            H1_h, w2, fc2_b, x1b_h, ln2_g, ln2_b, out, nullptr, mb);
    }
}

// Round 20
// 878.714 us; speedup vs baseline: 1.1360x; 1.1360x over previous
//
#include <hip/hip_runtime.h>
#include <hip/hip_bf16.h>
#include <math.h>

typedef __hip_bfloat16 bf16;
typedef __bf16 bf16x8 __attribute__((ext_vector_type(8)));
typedef float f32x4 __attribute__((ext_vector_type(4)));

#define HH 56
#define WW 56
#define WSZ 7
#define SSH 3
#define NHEAD 12
#define CDIM 384
#define BBATCH 32
#define NTOK 49
#define NWIN 64
#define HIDD 1536
#define HD 32
#define NWTOT (BBATCH*NWIN)
#define MROWS (NWTOT*NTOK)        /* 100352 */
#define MHALF (MROWS/2)           /* 50176 */
#define LTOT (HH*WW)
#define EPSLN 1e-5f
#define QSCALE 0.17677669529663687f
#define NEGBIG -1e30f

#define CVTBLK 6912               /* 1,769,472 / 256 */
#define TBLBLK 12288              /* 64*12*64*64 / 256 */

enum { M_QK = 0, M_V = 1, M_FC1 = 2 };

__device__ __forceinline__ void gload16(const void* g, void* l) {
    __builtin_amdgcn_global_load_lds(
        (const __attribute__((address_space(1))) void*)g,
        (__attribute__((address_space(3))) void*)l, 16, 0, 0);
}

__device__ __forceinline__ unsigned short bfbits(float v) {
    bf16 b = __float2bfloat16(v);
    return *reinterpret_cast<unsigned short*>(&b);
}

__device__ __forceinline__ float fast_gelu(float v) {
    return v / (1.0f + __expf(-1.59576912f * v * fmaf(0.044715f, v * v, 1.0f)));
}

__device__ __forceinline__ int xcd_swz(int orig, int nwg) {
    const int q = nwg >> 3, r = nwg & 7;
    const int xcd = orig & 7, loc = orig >> 3;
    return (xcd < r ? xcd * (q + 1) : r * (q + 1) + (xcd - r) * q) + loc;
}

// ---------------------------------------------------------------------------
// prep: weight conversions (blocks 0..CVTBLK-1) + bias/mask table (rest),
// one dispatch, block-uniform branch.
__global__ __launch_bounds__(256)
void prep_k(const float* __restrict__ s0, const float* __restrict__ s1,
            const float* __restrict__ s2, const float* __restrict__ s3,
            bf16* __restrict__ d0, bf16* __restrict__ d1,
            bf16* __restrict__ d2, bf16* __restrict__ d3,
            const float* __restrict__ rpb, const int* __restrict__ relidx,
            const float* __restrict__ amask, float* __restrict__ tbl) {
    if (blockIdx.x < CVTBLK) {
        int i = blockIdx.x * 256 + threadIdx.x;          // 1,769,472 total
        if (i < 442368)        d0[i] = __float2bfloat16(s0[i]);
        else if (i < 589824)  { int j = i - 442368;  d1[j] = __float2bfloat16(s1[j]); }
        else if (i < 1179648) { int j = i - 589824;  d2[j] = __float2bfloat16(s2[j]); }
        else                  { int j = i - 1179648; d3[j] = __float2bfloat16(s3[j]); }
    } else {
        int idx = (blockIdx.x - CVTBLK) * 256 + threadIdx.x;   // 64*12*64*64
        int m = idx & 63, n = (idx >> 6) & 63;
        int h = (idx >> 12) % NHEAD, wi = idx / (64 * 64 * NHEAD);
        float v;
        if (m >= NTOK) v = NEGBIG;
        else if (n >= NTOK) v = 0.f;
        else v = rpb[relidx[n * NTOK + m] * NHEAD + h] + amask[((long)wi * NTOK + n) * NTOK + m];
        tbl[idx] = v;
    }
}

__global__ __launch_bounds__(256) void gather_k(const float* __restrict__ x,
                                                bf16* __restrict__ xw, int rbase) {
    int idx = blockIdx.x * 256 + threadIdx.x;
    int rr_l = idx / 96, c4 = (idx % 96) * 4;
    int rr = rbase + rr_l;
    int w = rr / 49, ti = rr % 49;
    int b = w >> 6, wi = w & 63;
    int hy = (wi >> 3) * 7 + ti / 7;
    int hx = (wi & 7) * 7 + ti % 7;
    int sh = hy + SSH; if (sh >= HH) sh -= HH;
    int sw = hx + SSH; if (sw >= WW) sw -= WW;
    float4 v = *(const float4*)&x[((long)b * LTOT + sh * WW + sw) * CDIM + c4];
    ushort4 u = { bfbits(v.x), bfbits(v.y), bfbits(v.z), bfbits(v.w) };
    *(ushort4*)&xw[(long)rr_l * CDIM + c4] = u;
}

// ---------------------------------------------------------------------------
// MFMA GEMM. 128x128 tile, BK=32, 4 waves, LDS 32 KB, 4 blk/CU (R12/R16/R18
// best, 886 us reproduced 3x). Counted-vmcnt dbuf pipeline, sched_barrier
// pins, T2 swizzle. ONE schedule per instantiation. SWAP != M_V.
// ---------------------------------------------------------------------------
template<int MODE, int KDIM, int NTN>
__global__ __launch_bounds__(256, 4)
void mgemm_k(const bf16* __restrict__ A, const bf16* __restrict__ Wt,
             const float* __restrict__ bias, void* __restrict__ Outp)
{
    constexpr bool SWAP = (MODE != M_V);
    __shared__ bf16 As[2][128 * 32];
    __shared__ bf16 Bs[2][128 * 32];
    const int tid = threadIdx.x;
    const int wid = tid >> 6, lane = tid & 63;

    const int gid = xcd_swz(blockIdx.x, gridDim.x);
    const int m0 = (gid / NTN) * 128;
    const int n0 = (gid % NTN) * 128;

    const int strow = lane >> 2, stseg = lane & 3;
    const int swseg = stseg ^ ((strow >> 1) & 3);
    const bf16* Ag = A + (long)(m0 + wid * 32 + strow) * KDIM + swseg * 8;
    const bf16* Wg = Wt + (long)(n0 + wid * 32 + strow) * KDIM + swseg * 8;

    const int wr = (wid >> 1) * 64, wc = (wid & 1) * 64;
    const int l15 = lane & 15, g4 = lane >> 4;
    const int sa = g4 ^ ((l15 >> 1) & 3);

    f32x4 acc[4][4] = {};

    auto STAGE = [&](int b, int t) {
#pragma unroll
        for (int i = 0; i < 2; ++i)
            gload16(Ag + (long)(i * 16) * KDIM + t * 32, &As[b][(wid * 32 + i * 16) * 32]);
#pragma unroll
        for (int i = 0; i < 2; ++i)
            gload16(Wg + (long)(i * 16) * KDIM + t * 32, &Bs[b][(wid * 32 + i * 16) * 32]);
    };

    const int nt = KDIM / 32;
    STAGE(0, 0);
    STAGE(1, 1);
    asm volatile("s_waitcnt vmcnt(4)" ::: "memory");
    __builtin_amdgcn_s_barrier();

    int buf = 0;
    for (int t = 0; t < nt; ++t) {
        bf16x8 af[4], bfr[4];
#pragma unroll
        for (int i = 0; i < 4; ++i) {
            af[i]  = *(const bf16x8*)&As[buf][(wr + i * 16 + l15) * 32 + sa * 8];
            bfr[i] = *(const bf16x8*)&Bs[buf][(wc + i * 16 + l15) * 32 + sa * 8];
        }
        __builtin_amdgcn_sched_barrier(0);
        asm volatile("s_waitcnt lgkmcnt(0)" ::: "memory");
        __builtin_amdgcn_sched_barrier(0);
        __builtin_amdgcn_s_barrier();
        if (t + 2 < nt) STAGE(buf, t + 2);
#pragma unroll
        for (int mi = 0; mi < 4; ++mi)
#pragma unroll
            for (int ni = 0; ni < 4; ++ni) {
                if (SWAP)
                    acc[ni][mi] = __builtin_amdgcn_mfma_f32_16x16x32_bf16(
                        bfr[ni], af[mi], acc[ni][mi], 0, 0, 0);
                else
                    acc[mi][ni] = __builtin_amdgcn_mfma_f32_16x16x32_bf16(
                        af[mi], bfr[ni], acc[mi][ni], 0, 0, 0);
            }
        if (t + 2 < nt) { asm volatile("s_waitcnt vmcnt(4)" ::: "memory"); }
        else            { asm volatile("s_waitcnt vmcnt(0)" ::: "memory"); }
        __builtin_amdgcn_s_barrier();
        buf ^= 1;
    }

    if (MODE == M_V) {
#pragma unroll
        for (int mi = 0; mi < 4; ++mi) {
            const int mb = m0 + wr + mi * 16 + g4 * 4;
            const int wv_ = mb / 49, ti0 = mb - wv_ * 49;
#pragma unroll
            for (int ni = 0; ni < 4; ++ni) {
                const int n = n0 + wc + ni * 16 + l15;
                const int h = n >> 5, d = n & 31;
                const float bn = bias[n];
                float v4[4];
#pragma unroll
                for (int j = 0; j < 4; ++j) v4[j] = acc[mi][ni][j] + bn;
                if (ti0 <= 45) {
                    ushort4 u = { bfbits(v4[0]), bfbits(v4[1]), bfbits(v4[2]), bfbits(v4[3]) };
                    *(ushort4*)&((bf16*)Outp)[(((long)wv_ * NHEAD + h) * HD + d) * 64 + ti0] = u;
                } else {
#pragma unroll
                    for (int j = 0; j < 4; ++j) {
                        const int m = mb + j;
                        const int w2 = m / 49, ti = m - w2 * 49;
                        ((bf16*)Outp)[(((long)w2 * NHEAD + h) * HD + d) * 64 + ti]
                            = __float2bfloat16(v4[j]);
                    }
                }
            }
        }
    } else {
        long rowbase[4];
        int wq_[4], ti_[4];
#pragma unroll
        for (int mi = 0; mi < 4; ++mi) {
            const int m = m0 + wr + mi * 16 + l15;
            if (MODE == M_QK) { wq_[mi] = m / 49; ti_[mi] = m - wq_[mi] * 49; }
            else              { rowbase[mi] = (long)m * HIDD; }
        }
#pragma unroll
        for (int ni = 0; ni < 4; ++ni) {
            const int nb = n0 + wc + ni * 16 + g4 * 4;
            const float4 bn = *(const float4*)&bias[nb];
            const float bb[4] = { bn.x, bn.y, bn.z, bn.w };
#pragma unroll
            for (int mi = 0; mi < 4; ++mi) {
                float v4[4];
#pragma unroll
                for (int j = 0; j < 4; ++j) v4[j] = acc[ni][mi][j] + bb[j];
                if (MODE == M_FC1) {
#pragma unroll
                    for (int j = 0; j < 4; ++j) v4[j] = fast_gelu(v4[j]);
                } else if (MODE == M_QK) {
                    if (nb < CDIM) {
#pragma unroll
                        for (int j = 0; j < 4; ++j) v4[j] *= QSCALE;
                    }
                }
                ushort4 u = { bfbits(v4[0]), bfbits(v4[1]), bfbits(v4[2]), bfbits(v4[3]) };
                if (MODE == M_QK) {
                    const int which = nb >= CDIM;
                    const int hb = (nb - which * CDIM) >> 5, d0 = nb & 31;
                    *(ushort4*)&((bf16*)Outp)[
                        ((((long)wq_[mi] * 2 + which) * NHEAD + hb) * NTOK + ti_[mi]) * HD + d0] = u;
                } else {
                    *(ushort4*)&((bf16*)Outp)[rowbase[mi] + nb] = u;
                }
            }
        }
    }
}

// ---------------------------------------------------------------------------
// Fused GEMM(128 x 384 x K) + row-LayerNorm + residual (R12/R16/R18 shape).
// ---------------------------------------------------------------------------
template<int KDIM, bool SCATTER>
__global__ __launch_bounds__(512, 2)
void gemm_ln_k(const bf16* __restrict__ A, const bf16* __restrict__ Wt,
               const float* __restrict__ bias, const bf16* __restrict__ resid,
               const float* __restrict__ lng, const float* __restrict__ lnb,
               float* __restrict__ outf, bf16* __restrict__ outb, int mbase)
{
    __shared__ bf16 As[2][128 * 32];     // 16 KB
    __shared__ bf16 Bs[2][384 * 32];     // 48 KB
    __shared__ float lnp[1024];          // 4 KB
    const int tid = threadIdx.x;
    const int wid = tid >> 6, lane = tid & 63;

    const int m0 = xcd_swz(blockIdx.x, gridDim.x) * 128;

    const int strow = tid >> 2, stseg = tid & 3;
    const int sws = stseg ^ ((strow >> 1) & 3);
    const bf16* Ag = A + (long)(m0 + strow) * KDIM + sws * 8;
    const bf16* Wg = Wt + (long)strow * KDIM + sws * 8;

    const int wm = wid >> 2, wn = wid & 3;
    const int wr = wm * 64, wc = wn * 96;
    const int l15 = lane & 15, g4 = lane >> 4;
    const int sa = g4 ^ ((l15 >> 1) & 3);

    f32x4 acc[6][4] = {};

    auto STAGE = [&](int b, int t) {
        gload16(Ag + t * 32, &As[b][strow * 32 + stseg * 8]);
#pragma unroll
        for (int p = 0; p < 3; ++p)
            gload16(Wg + (long)(p * 128) * KDIM + t * 32,
                    &Bs[b][(p * 128 + strow) * 32 + stseg * 8]);
    };

    const int nt = KDIM / 32;
    STAGE(0, 0);
    STAGE(1, 1);
    asm volatile("s_waitcnt vmcnt(4)" ::: "memory");
    __builtin_amdgcn_s_barrier();

    int buf = 0;
    for (int t = 0; t < nt; ++t) {
        bf16x8 af[4], bfr[6];
#pragma unroll
        for (int i = 0; i < 4; ++i)
            af[i] = *(const bf16x8*)&As[buf][(wr + i * 16 + l15) * 32 + sa * 8];
#pragma unroll
        for (int i = 0; i < 6; ++i)
            bfr[i] = *(const bf16x8*)&Bs[buf][(wc + i * 16 + l15) * 32 + sa * 8];
        __builtin_amdgcn_sched_barrier(0);
        asm volatile("s_waitcnt lgkmcnt(0)" ::: "memory");
        __builtin_amdgcn_sched_barrier(0);
        __builtin_amdgcn_s_barrier();
        if (t + 2 < nt) STAGE(buf, t + 2);
#pragma unroll
        for (int ni = 0; ni < 6; ++ni)
#pragma unroll
            for (int mi = 0; mi < 4; ++mi)
                acc[ni][mi] = __builtin_amdgcn_mfma_f32_16x16x32_bf16(
                    bfr[ni], af[mi], acc[ni][mi], 0, 0, 0);
        if (t + 2 < nt) { asm volatile("s_waitcnt vmcnt(4)" ::: "memory"); }
        else            { asm volatile("s_waitcnt vmcnt(0)" ::: "memory"); }
        __builtin_amdgcn_s_barrier();
        buf ^= 1;
    }

    float psum[4] = {}, psq[4] = {};
#pragma unroll
    for (int ni = 0; ni < 6; ++ni) {
        const int nb = wc + ni * 16 + g4 * 4;
        const float4 bn = *(const float4*)&bias[nb];
        const float bb[4] = { bn.x, bn.y, bn.z, bn.w };
#pragma unroll
        for (int mi = 0; mi < 4; ++mi)
#pragma unroll
            for (int j = 0; j < 4; ++j) {
                float v = acc[ni][mi][j] + bb[j];
                acc[ni][mi][j] = v;
                psum[mi] += v; psq[mi] += v * v;
            }
    }
#pragma unroll
    for (int mi = 0; mi < 4; ++mi) {
        psum[mi] += __shfl_xor(psum[mi], 16); psum[mi] += __shfl_xor(psum[mi], 32);
        psq[mi]  += __shfl_xor(psq[mi], 16);  psq[mi]  += __shfl_xor(psq[mi], 32);
    }
    if (g4 == 0) {
#pragma unroll
        for (int mi = 0; mi < 4; ++mi) {
            const int r = wr + mi * 16 + l15;
            lnp[wn * 128 + r] = psum[mi];
            lnp[512 + wn * 128 + r] = psq[mi];
        }
    }
    __syncthreads();

#pragma unroll
    for (int mi = 0; mi < 4; ++mi) {
        const int r = wr + mi * 16 + l15;
        const float s  = lnp[r] + lnp[128 + r] + lnp[256 + r] + lnp[384 + r];
        const float sq = lnp[512 + r] + lnp[640 + r] + lnp[768 + r] + lnp[896 + r];
        const float mean = s * (1.f / 384.f);
        const float rstd = rsqrtf(sq * (1.f / 384.f) - mean * mean + EPSLN);

        const long rl = m0 + r;
        long dst;
        if (SCATTER) {
            const int m = mbase + (int)rl;
            int w = m / 49, ti = m - w * 49;
            int b = w >> 6, wi = w & 63;
            int hy = (wi >> 3) * 7 + ti / 7;
            int hx = (wi & 7) * 7 + ti % 7;
            int dh = hy + SSH; if (dh >= HH) dh -= HH;
            int dw = hx + SSH; if (dw >= WW) dw -= WW;
            dst = (long)b * LTOT + dh * WW + dw - mbase;
        } else {
            dst = mbase + rl;
        }
#pragma unroll
        for (int ni = 0; ni < 6; ++ni) {
            const int c = wc + ni * 16 + g4 * 4;
            const float4 gv = *(const float4*)&lng[c];
            const float4 bv = *(const float4*)&lnb[c];
            ushort4 xv = *(const ushort4*)&resid[rl * CDIM + c];
            float x0 = __bfloat162float(*(bf16*)&xv.x);
            float x1 = __bfloat162float(*(bf16*)&xv.y);
            float x2 = __bfloat162float(*(bf16*)&xv.z);
            float x3 = __bfloat162float(*(bf16*)&xv.w);
            float r0 = x0 + (acc[ni][mi][0] - mean) * rstd * gv.x + bv.x;
            float r1 = x1 + (acc[ni][mi][1] - mean) * rstd * gv.y + bv.y;
            float r2 = x2 + (acc[ni][mi][2] - mean) * rstd * gv.z + bv.z;
            float r3 = x3 + (acc[ni][mi][3] - mean) * rstd * gv.w + bv.w;
            if (SCATTER) {
                ushort4 u = { bfbits(r0), bfbits(r1), bfbits(r2), bfbits(r3) };
                *(ushort4*)&outb[dst * CDIM + c] = u;
            } else {
                float4 o = { r0, r1, r2, r3 };
                *(float4*)&outf[dst * CDIM + c] = o;
            }
        }
    }
}

// ---------------------------------------------------------------------------
// MFMA attention: 4 waves/block, each wave = one (window, head). Unchanged.
// ---------------------------------------------------------------------------
__global__ __launch_bounds__(256)
void mattn_k(const bf16* __restrict__ qk, const bf16* __restrict__ vT,
             const float* __restrict__ tbl, bf16* __restrict__ attn_out)
{
    __shared__ bf16 Plds[4][64 * 72];
    const int tid = threadIdx.x, wid = tid >> 6, lane = tid & 63;
    const int t = blockIdx.x * 4 + wid;
    const int w = t / NHEAD, h = t % NHEAD, wi = w & 63;
    const int l15 = lane & 15, g = lane >> 4;
    const bf16* qb = qk + ((long)(w * 2 + 0) * NHEAD + h) * (NTOK * HD);
    const bf16* kb = qk + ((long)(w * 2 + 1) * NHEAD + h) * (NTOK * HD);
    const bf16* vt = vT + ((long)w * NHEAD + h) * (HD * 64);
    const float* Tb = tbl + (long)(wi * NHEAD + h) * 64 * 64;
    char* Pw = (char*)&Plds[wid][0];

    bf16x8 kf[4], qf[4];
#pragma unroll
    for (int i = 0; i < 4; ++i) {
        kf[i] = *(const bf16x8*)&kb[(16 * i + l15) * HD + 8 * g];
        qf[i] = *(const bf16x8*)&qb[(16 * i + l15) * HD + 8 * g];
    }
    f32x4 s[4][4] = {};
#pragma unroll
    for (int mi = 0; mi < 4; ++mi)
#pragma unroll
        for (int ni = 0; ni < 4; ++ni)
            s[mi][ni] = __builtin_amdgcn_mfma_f32_16x16x32_bf16(
                kf[mi], qf[ni], s[mi][ni], 0, 0, 0);

#pragma unroll
    for (int ni = 0; ni < 4; ++ni) {
        const int n = 16 * ni + l15;
#pragma unroll
        for (int mi = 0; mi < 4; ++mi) {
            float4 tv = *(const float4*)&Tb[(long)n * 64 + 16 * mi + 4 * g];
            s[mi][ni][0] += tv.x; s[mi][ni][1] += tv.y;
            s[mi][ni][2] += tv.z; s[mi][ni][3] += tv.w;
        }
        float mx = NEGBIG;
#pragma unroll
        for (int mi = 0; mi < 4; ++mi)
#pragma unroll
            for (int j = 0; j < 4; ++j) mx = fmaxf(mx, s[mi][ni][j]);
        mx = fmaxf(mx, __shfl_xor(mx, 16));
        mx = fmaxf(mx, __shfl_xor(mx, 32));
        float sum = 0.f;
#pragma unroll
        for (int mi = 0; mi < 4; ++mi)
#pragma unroll
            for (int j = 0; j < 4; ++j) {
                float e = expf(s[mi][ni][j] - mx);
                s[mi][ni][j] = e; sum += e;
            }
        sum += __shfl_xor(sum, 16);
        sum += __shfl_xor(sum, 32);
        const float r = 1.0f / sum;
#pragma unroll
        for (int mi = 0; mi < 4; ++mi) {
            ushort4 u;
            u.x = bfbits(s[mi][ni][0] * r);
            u.y = bfbits(s[mi][ni][1] * r);
            u.z = bfbits(s[mi][ni][2] * r);
            u.w = bfbits(s[mi][ni][3] * r);
            *(ushort4*)(Pw + (long)n * 144 + (16 * mi + 4 * g) * 2) = u;
        }
    }

    f32x4 o[4][2] = {};
#pragma unroll
    for (int kk = 0; kk < 2; ++kk) {
        bf16x8 vf[2];
        vf[0] = *(const bf16x8*)&vt[(long)(l15) * 64 + 32 * kk + 8 * g];
        vf[1] = *(const bf16x8*)&vt[(long)(16 + l15) * 64 + 32 * kk + 8 * g];
#pragma unroll
        for (int rt = 0; rt < 4; ++rt) {
            bf16x8 pf = *(const bf16x8*)(Pw + (long)(16 * rt + l15) * 144 + (32 * kk + 8 * g) * 2);
            o[rt][0] = __builtin_amdgcn_mfma_f32_16x16x32_bf16(pf, vf[0], o[rt][0], 0, 0, 0);
            o[rt][1] = __builtin_amdgcn_mfma_f32_16x16x32_bf16(pf, vf[1], o[rt][1], 0, 0, 0);
        }
    }

#pragma unroll
    for (int rt = 0; rt < 4; ++rt)
#pragma unroll
        for (int dt = 0; dt < 2; ++dt)
#pragma unroll
            for (int j = 0; j < 4; ++j) {
                int n = 16 * rt + 4 * g + j;
                if (n < NTOK)
                    attn_out[((long)w * NTOK + n) * CDIM + h * HD + 16 * dt + l15]
                        = __float2bfloat16(o[rt][dt][j]);
            }
}

extern "C" void kernel_launch(void* const* d_in, const int* in_sizes, int n_in,
                              void* d_out, int out_size, void* d_ws, size_t ws_size,
                              hipStream_t stream)
{
    const float* x      = (const float*)d_in[0];
    const float* qkv_w  = (const float*)d_in[1];
    const float* qkv_b  = (const float*)d_in[2];
    const float* proj_w = (const float*)d_in[3];
    const float* proj_b = (const float*)d_in[4];
    const float* rpb    = (const float*)d_in[5];
    const float* ln1_g  = (const float*)d_in[6];
    const float* ln1_b  = (const float*)d_in[7];
    const float* fc1_w  = (const float*)d_in[8];
    const float* fc1_b  = (const float*)d_in[9];
    const float* fc2_w  = (const float*)d_in[10];
    const float* fc2_b  = (const float*)d_in[11];
    const float* ln2_g  = (const float*)d_in[12];
    const float* ln2_b  = (const float*)d_in[13];
    const float* amask  = (const float*)d_in[14];
    const int*   relidx = (const int*)d_in[15];
    float* out = (float*)d_out;
    char*  ws  = (char*)d_ws;

    // workspace layout (half-pipelined; peak 259,129,344 B)
    bf16*  wq    = (bf16*) (ws + 0L);
    bf16*  wp    = (bf16*) (ws + 884736L);
    bf16*  w1    = (bf16*) (ws + 1179648L);
    bf16*  w2    = (bf16*) (ws + 2359296L);
    float* tbl   = (float*)(ws + 3538944L);
    bf16*  xw_h  = (bf16*) (ws + 16121856L);
    bf16*  qkb_h = (bf16*) (ws + 54657024L);
    bf16*  vT_h  = (bf16*) (ws + 131727360L);
    bf16*  att_h = (bf16*) (ws + 182059008L);
    bf16*  x1b_h = (bf16*) (ws + 220594176L);
    bf16*  H1_h  = (bf16*) (ws + 16121856L);

    dim3 b256(256), b512(512);

    // 0. prep: weights + bias/mask table in ONE dispatch
    prep_k<<<dim3(CVTBLK + TBLBLK), b256, 0, stream>>>(
        qkv_w, proj_w, fc1_w, fc2_w, wq, wp, w1, w2, rpb, relidx, amask, tbl);

    for (int c = 0; c < 2; ++c) {
        const int mb = c * MHALF;
        gather_k<<<dim3(MHALF * 96 / 256), b256, 0, stream>>>(x, xw_h, mb);
        mgemm_k<M_QK, CDIM, 6><<<dim3((MHALF/128)*6), b256, 0, stream>>>(
            xw_h, wq, qkv_b, (void*)qkb_h);
        mgemm_k<M_V, CDIM, 3><<<dim3((MHALF/128)*3), b256, 0, stream>>>(
            xw_h, wq + (long)2*CDIM*CDIM, qkv_b + 2*CDIM, (void*)vT_h);
        mattn_k<<<dim3(1024 * NHEAD / 4), b256, 0, stream>>>(qkb_h, vT_h, tbl, att_h);
        // PROJ + LN1 + residual(xw) + window-reverse scatter -> x1b (bf16)
        gemm_ln_k<CDIM, true><<<dim3(MHALF/128), b512, 0, stream>>>(
            att_h, wp, proj_b, xw_h, ln1_g, ln1_b, nullptr, x1b_h, mb);
        // FC1 + fast-gelu -> H1
        mgemm_k<M_FC1, CDIM, 12><<<dim3((MHALF/128)*12), b256, 0, stream>>>(
            x1b_h, w1, fc1_b, (void*)H1_h);
        // FC2 + LN2 + residual(x1b) -> out (fp32)
        gemm_ln_k<HIDD, false><<<dim3(MHALF/128), b512, 0, stream>>>(
            H1_h, w2, fc2_b, x1b_h, ln2_g, ln2_b, out, nullptr, mb);
    }
}